// Round 9
// baseline (62.848 us; speedup 1.0000x reference)
//
#include <hip/hip_runtime.h>

// CTC batch loss forward (Keras ctc_batch_cost semantics).
// B=2048, T=256, L=32, V=128, blank=V-1=127, S=2L+1=65.
// Producer/consumer wave split per batch item (block = 128 threads):
//   wave 0 (producer): streams FULL rows into LDS via global_load_lds
//     dwordx4 (8 instr / 16-row chunk), triple-buffered, counted vmcnt.
//   wave 1 (consumer): per chunk, gathers its sym column from LDS
//     (ds_read_b32, blank lanes broadcast), computes lp2 = log2(p+eps)
//     off-chain, then runs the pure-register CTC DP:
//     lane l owns extended state l+1; state 0 = uniform running sum b0;
//     alpha2 = m + log2(p) streaming-softmax form; cross-lane via DPP
//     wave_shr:1 (VALU pipe); p folded into m every 8 steps.

constexpr int Bb = 2048;
constexpr int Tt = 256;
constexpr int Ll = 32;
constexpr int Vv = 128;
constexpr int BLANK = Vv - 1;
constexpr int CHUNK = 16;
constexpr int NCH = Tt / CHUNK;     // 16
#define EPSF 1e-7f
#define NEGF -1e30f
#define LN2F 0.6931471805599453f

#define GLOBAL_AS(p) ((const __attribute__((address_space(1))) void*)(p))
#define LDS_AS(p)    ((__attribute__((address_space(3))) void*)(p))

__device__ __forceinline__ float fexp2(float x) { return __builtin_amdgcn_exp2f(x); }
__device__ __forceinline__ float flog2(float x) { return __builtin_amdgcn_logf(x); }
__device__ __forceinline__ float rdlane(float v, int l) {
    return __uint_as_float(__builtin_amdgcn_readlane(__float_as_uint(v), l));
}
// whole-wave shift-up-by-1 in the VALU pipe; lane 0 receives `old`
__device__ __forceinline__ float dpp_shr1(float old, float src) {
    return __int_as_float(__builtin_amdgcn_update_dpp(
        __float_as_int(old), __float_as_int(src), 0x138 /*WAVE_SHR1*/,
        0xf, 0xf, false));
}

__global__ __launch_bounds__(128) void ctc_fwd(const int* __restrict__ y_true,
                                               const float* __restrict__ y_pred,
                                               float* __restrict__ out) {
    const int w    = blockIdx.x;            // batch item
    const int wave = threadIdx.x >> 6;      // 0 = producer, 1 = consumer
    const int lane = threadIdx.x & 63;

    __shared__ float buf[3][CHUNK * Vv];    // raw prob rows, 3 x 8 KB

    if (wave == 0) {
        // ---------------- producer: pure streaming ----------------
        const float* gbase = y_pred + (size_t)w * Tt * Vv;
        auto issue = [&](int c, float* dst) {
            const float* g = gbase + (size_t)c * (CHUNK * Vv) + lane * 4;
            float*       l = dst + lane * 4;
#pragma unroll
            for (int i = 0; i < 8; ++i)
                __builtin_amdgcn_global_load_lds(GLOBAL_AS(g + i * 256),
                                                 LDS_AS(l + i * 256), 16, 0, 0);
        };
        issue(0, buf[0]);
        for (int c = 0; c < NCH; ++c) {
            if (c + 1 < NCH) {
                issue(c + 1, buf[(c + 1) % 3]);
                // chunk c's 8 loads done; chunk c+1's 8 stay in flight
                asm volatile("s_waitcnt vmcnt(8)" ::: "memory");
            } else {
                asm volatile("s_waitcnt vmcnt(0)" ::: "memory");
            }
            __syncthreads();
        }
    } else {
        // ---------------- consumer: LDS gather + register DP ----------------
        // lane l owns state l+1: even lane -> label l/2, odd lane -> blank
        int sym = BLANK;
        if (!(lane & 1)) sym = y_true[w * Ll + (lane >> 1)];
        const int  symm2 = __shfl_up(sym, 2);
        const bool skip  = !(lane & 1) && (lane >= 2) && (sym != symm2);

        float m = NEGF, p = 1.0f, b0 = 0.0f;

        auto step = [&](float lp2) {
            const float lpb = rdlane(lp2, 1);        // blank lp (uniform)
            const float b0p = b0;
            const float m1g = dpp_shr1(b0p,  m);     // s-1 (lane0 <- state 0)
            const float p1g = dpp_shr1(1.0f, p);
            const float m2s = dpp_shr1(NEGF, m1g);   // s-2
            const float p2g = dpp_shr1(1.0f, p1g);
            const float m2g = skip ? m2s : NEGF;
            const float hi  = fmaxf(fmaxf(m, m1g), m2g);   // -> v_max3
            const float pn  = p   * fexp2(m   - hi)
                            + p1g * fexp2(m1g - hi)
                            + p2g * fexp2(m2g - hi);       // dead terms weigh 0
            m  = hi + lp2;
            p  = pn;
            b0 = b0p + lpb;                          // state 0 self-loop
        };
        auto renorm = [&]() {   // p <= 3^8 between renorms, fp32-safe
            m += flog2(fmaxf(p, 1e-30f));  p = 1.0f;
        };

        for (int c = 0; c < NCH; ++c) {
            __syncthreads();                         // chunk c resident
            const float* src = buf[c % 3];
            float lp[CHUNK];
#pragma unroll
            for (int i = 0; i < CHUNK; ++i)
                lp[i] = flog2(src[i * Vv + sym] + EPSF);
            if (c == 0) {
                // t=0 init: alpha[1] on lane 0; b0 = blank lp (lane 1's value)
                b0 = rdlane(lp[0], 1);
                m  = (lane == 0) ? lp[0] : NEGF;
                p  = 1.0f;
#pragma unroll
                for (int i = 1; i < CHUNK; ++i) {
                    step(lp[i]);
                    if ((i & 7) == 7) renorm();
                }
            } else {
#pragma unroll
                for (int i = 0; i < CHUNK; ++i) {
                    step(lp[i]);
                    if ((i & 7) == 7) renorm();
                }
            }
        }

        // loss = -ln2 * logaddexp2(alpha2[63](=lane62), alpha2[64](=lane63))
        const float afin = m + flog2(fmaxf(p, 1e-30f));
        const float aA = rdlane(afin, 62);
        const float aB = rdlane(afin, 63);
        if (lane == 0) {
            const float h = fmaxf(aA, aB);
            const float r = h + flog2(fexp2(aA - h) + fexp2(aB - h));
            out[w] = -r * LN2F;
        }
    }
}

extern "C" void kernel_launch(void* const* d_in, const int* in_sizes, int n_in,
                              void* d_out, int out_size, void* d_ws, size_t ws_size,
                              hipStream_t stream) {
    const int*   y_true = (const int*)d_in[0];
    const float* y_pred = (const float*)d_in[1];
    float*       out    = (float*)d_out;
    ctc_fwd<<<dim3(Bb), dim3(128), 0, stream>>>(y_true, y_pred, out);
}

// Round 10
// 49.702 us; speedup vs baseline: 1.2645x; 1.2645x over previous
//
#include <hip/hip_runtime.h>

// CTC batch loss forward (Keras ctc_batch_cost semantics).
// B=2048, T=256, L=32, V=128, blank=V-1=127, S=2L+1=65.
// Block = 256 threads per batch item: 3 producer waves + 1 consumer wave.
//   producers (waves 1..3): round-robin over 16-row chunks (p owns c%3==p).
//     Register-gather y_pred[b][t][sym_lane] (R8-proven HBM path), flog2,
//     write lp2 to a 4-slot LDS ring. Loads for chunk c+3 are issued right
//     after barrier c -> ~2 chunk-periods of latency cover, ~24 staggered
//     gather streams per CU (smooth, deep issue).
//   consumer (wave 0): pure-register CTC DP. Lane l owns extended state l+1;
//     state 0 (first blank, self-loop) is a uniform running sum b0;
//     alpha2 = m + log2(p) streaming-softmax form; cross-lane via DPP
//     wave_shr:1 (VALU pipe); p folded into m every 8 steps.
// One __syncthreads per chunk (16 total) publishes chunk c.

constexpr int Bb = 2048;
constexpr int Tt = 256;
constexpr int Ll = 32;
constexpr int Vv = 128;
constexpr int BLANK = Vv - 1;
constexpr int CHUNK = 16;
constexpr int NCH = Tt / CHUNK;     // 16
constexpr int SLOTS = 4;            // LDS ring depth (16 KB)
#define EPSF 1e-7f
#define NEGF -1e30f
#define LN2F 0.6931471805599453f

__device__ __forceinline__ float fexp2(float x) { return __builtin_amdgcn_exp2f(x); }
__device__ __forceinline__ float flog2(float x) { return __builtin_amdgcn_logf(x); }
__device__ __forceinline__ float rdlane(float v, int l) {
    return __uint_as_float(__builtin_amdgcn_readlane(__float_as_uint(v), l));
}
// whole-wave shift-up-by-1 in the VALU pipe; lane 0 receives `old`
__device__ __forceinline__ float dpp_shr1(float old, float src) {
    return __int_as_float(__builtin_amdgcn_update_dpp(
        __float_as_int(old), __float_as_int(src), 0x138 /*WAVE_SHR1*/,
        0xf, 0xf, false));
}

__global__ __launch_bounds__(256) void ctc_fwd(const int* __restrict__ y_true,
                                               const float* __restrict__ y_pred,
                                               float* __restrict__ out) {
    const int w    = blockIdx.x;            // batch item
    const int wave = threadIdx.x >> 6;      // 0 = consumer, 1..3 = producers
    const int lane = threadIdx.x & 63;

    __shared__ float buf[SLOTS][CHUNK][64]; // lp2 ring, 16 KB

    // lane l owns state l+1: even lane -> label l/2, odd lane -> blank
    int sym = BLANK;
    if (!(lane & 1)) sym = y_true[w * Ll + (lane >> 1)];

    if (wave >= 1) {
        // ---------------- producers ----------------
        const int p = wave - 1;             // 0,1,2: owns chunks c%3 == p
        const float* rp = y_pred + (size_t)w * Tt * Vv + sym;
        float r[CHUNK];
        // prologue: issue own first chunk (p)
#pragma unroll
        for (int i = 0; i < CHUNK; ++i) r[i] = rp[(size_t)(p * CHUNK + i) * Vv];
        for (int c = 0; c < NCH; ++c) {
            if (c % 3 == p) {
                // finalize chunk c (compiler inserts vmcnt waits at use)
#pragma unroll
                for (int i = 0; i < CHUNK; ++i)
                    buf[c & (SLOTS - 1)][i][lane] = flog2(r[i] + EPSF);
            }
            __syncthreads();                // publish chunk c
            if (c % 3 == p && c + 3 < NCH) {
                // issue chunk c+3 now; not needed until barrier c+3
#pragma unroll
                for (int i = 0; i < CHUNK; ++i)
                    r[i] = rp[(size_t)((c + 3) * CHUNK + i) * Vv];
            }
        }
    } else {
        // ---------------- consumer: register DP ----------------
        const int  symm2 = __shfl_up(sym, 2);
        const bool skip  = !(lane & 1) && (lane >= 2) && (sym != symm2);

        float m = NEGF, p = 1.0f, b0 = 0.0f;

        auto step = [&](float lp2) {
            const float lpb = rdlane(lp2, 1);        // blank lp (uniform)
            const float b0p = b0;
            const float m1g = dpp_shr1(b0p,  m);     // s-1 (lane0 <- state 0)
            const float p1g = dpp_shr1(1.0f, p);
            const float m2s = dpp_shr1(NEGF, m1g);   // s-2
            const float p2g = dpp_shr1(1.0f, p1g);
            const float m2g = skip ? m2s : NEGF;
            const float hi  = fmaxf(fmaxf(m, m1g), m2g);   // -> v_max3
            const float pn  = p   * fexp2(m   - hi)
                            + p1g * fexp2(m1g - hi)
                            + p2g * fexp2(m2g - hi);       // dead terms weigh 0
            m  = hi + lp2;
            p  = pn;
            b0 = b0p + lpb;                          // state 0 self-loop
        };
        auto renorm = [&]() {   // p <= 3^8 between renorms, fp32-safe
            m += flog2(fmaxf(p, 1e-30f));  p = 1.0f;
        };

        for (int c = 0; c < NCH; ++c) {
            __syncthreads();                         // chunk c published
            float lp[CHUNK];
#pragma unroll
            for (int i = 0; i < CHUNK; ++i) lp[i] = buf[c & (SLOTS - 1)][i][lane];
            if (c == 0) {
                // t=0 init: alpha[1] on lane 0; b0 = blank lp (lane 1's value)
                b0 = rdlane(lp[0], 1);
                m  = (lane == 0) ? lp[0] : NEGF;
                p  = 1.0f;
#pragma unroll
                for (int i = 1; i < CHUNK; ++i) {
                    step(lp[i]);
                    if ((i & 7) == 7) renorm();
                }
            } else {
#pragma unroll
                for (int i = 0; i < CHUNK; ++i) {
                    step(lp[i]);
                    if ((i & 7) == 7) renorm();
                }
            }
        }

        // loss = -ln2 * logaddexp2(alpha2[63](=lane62), alpha2[64](=lane63))
        const float afin = m + flog2(fmaxf(p, 1e-30f));
        const float aA = rdlane(afin, 62);
        const float aB = rdlane(afin, 63);
        if (lane == 0) {
            const float h = fmaxf(aA, aB);
            const float r = h + flog2(fexp2(aA - h) + fexp2(aB - h));
            out[w] = -r * LN2F;
        }
    }
}

extern "C" void kernel_launch(void* const* d_in, const int* in_sizes, int n_in,
                              void* d_out, int out_size, void* d_ws, size_t ws_size,
                              hipStream_t stream) {
    const int*   y_true = (const int*)d_in[0];
    const float* y_pred = (const float*)d_in[1];
    float*       out    = (float*)d_out;
    ctc_fwd<<<dim3(Bb), dim3(256), 0, stream>>>(y_true, y_pred, out);
}

// Round 11
// 46.730 us; speedup vs baseline: 1.3449x; 1.0636x over previous
//
#include <hip/hip_runtime.h>

// CTC batch loss forward (Keras ctc_batch_cost semantics).
// B=2048, T=256, L=32, V=128, blank=V-1=127, S=2L+1=65.
// Producer/consumer wave split per batch item (block = 128 threads):
//   wave 0 (producer): register-gathers y_pred[b][t][sym_lane] per row with a
//     ring of FOUR 16-row chunk buffers, issue-lead 2 (loads for chunk c+2
//     issued at barrier c) -> every flog2-finalize has ~2 chunk-periods of
//     latency cover; no synchronous vmcnt drain anywhere. lp2 published to a
//     2-slot LDS ring, one __syncthreads per chunk.
//   wave 1 (consumer): pure-register CTC DP. Lane l owns extended state l+1
//     (even lane -> label l/2, odd lane -> blank; lane 63 -> state 64).
//     State 0 (first blank, self-loop) is a uniform running sum b0.
//     alpha2 = m + log2(p) streaming-softmax form; cross-lane via DPP
//     wave_shr:1 (VALU pipe); p folded into m every 8 steps.

constexpr int Bb = 2048;
constexpr int Tt = 256;
constexpr int Ll = 32;
constexpr int Vv = 128;
constexpr int BLANK = Vv - 1;
constexpr int CHUNK = 16;
constexpr int NCH = Tt / CHUNK;     // 16
#define EPSF 1e-7f
#define NEGF -1e30f
#define LN2F 0.6931471805599453f

__device__ __forceinline__ float fexp2(float x) { return __builtin_amdgcn_exp2f(x); }
__device__ __forceinline__ float flog2(float x) { return __builtin_amdgcn_logf(x); }
__device__ __forceinline__ float rdlane(float v, int l) {
    return __uint_as_float(__builtin_amdgcn_readlane(__float_as_uint(v), l));
}
// whole-wave shift-up-by-1 in the VALU pipe; lane 0 receives `old`
__device__ __forceinline__ float dpp_shr1(float old, float src) {
    return __int_as_float(__builtin_amdgcn_update_dpp(
        __float_as_int(old), __float_as_int(src), 0x138 /*WAVE_SHR1*/,
        0xf, 0xf, false));
}

__global__ __launch_bounds__(128) void ctc_fwd(const int* __restrict__ y_true,
                                               const float* __restrict__ y_pred,
                                               float* __restrict__ out) {
    const int w    = blockIdx.x;            // batch item
    const int wave = threadIdx.x >> 6;      // 0 = producer, 1 = consumer
    const int lane = threadIdx.x & 63;

    __shared__ float buf[2][CHUNK][64];     // lp2 ring, 8 KB

    // lane l owns state l+1: even lane -> label l/2, odd lane -> blank
    int sym = BLANK;
    if (!(lane & 1)) sym = y_true[w * Ll + (lane >> 1)];

    if (wave == 0) {
        // ---------------- producer: 4-buffer register ring, lead 2 ----------
        const float* rp = y_pred + (size_t)w * Tt * Vv + sym;
        float r0[CHUNK], r1[CHUNK], r2[CHUNK], r3[CHUNK];

#define ISSUE(R, C)                                                     \
        do { if ((C) < NCH) {                                           \
            _Pragma("unroll")                                           \
            for (int i = 0; i < CHUNK; ++i)                             \
                R[i] = rp[(size_t)((C) * CHUNK + i) * Vv];              \
        } } while (0)
#define FINALIZE(R, C)                                                  \
        do {                                                            \
            _Pragma("unroll")                                           \
            for (int i = 0; i < CHUNK; ++i)                             \
                buf[(C) & 1][i][lane] = flog2(R[i] + EPSF);             \
            __syncthreads();                                            \
        } while (0)

        ISSUE(r0, 0);
        ISSUE(r1, 1);
        for (int cc = 0; cc < NCH; cc += 4) {
            FINALIZE(r0, cc + 0);  ISSUE(r2, cc + 2);
            FINALIZE(r1, cc + 1);  ISSUE(r3, cc + 3);
            FINALIZE(r2, cc + 2);  ISSUE(r0, cc + 4);
            FINALIZE(r3, cc + 3);  ISSUE(r1, cc + 5);
        }
#undef ISSUE
#undef FINALIZE
    } else {
        // ---------------- consumer: pure-register DP ----------------
        const int  symm2 = __shfl_up(sym, 2);
        const bool skip  = !(lane & 1) && (lane >= 2) && (sym != symm2);

        float m = NEGF, p = 1.0f, b0 = 0.0f;

        auto step = [&](float lp2) {
            const float lpb = rdlane(lp2, 1);        // blank lp (uniform)
            const float b0p = b0;
            const float m1g = dpp_shr1(b0p,  m);     // s-1 (lane0 <- state 0)
            const float p1g = dpp_shr1(1.0f, p);
            const float m2s = dpp_shr1(NEGF, m1g);   // s-2
            const float p2g = dpp_shr1(1.0f, p1g);
            const float m2g = skip ? m2s : NEGF;
            const float hi  = fmaxf(fmaxf(m, m1g), m2g);   // -> v_max3
            const float pn  = p   * fexp2(m   - hi)
                            + p1g * fexp2(m1g - hi)
                            + p2g * fexp2(m2g - hi);       // dead terms weigh 0
            m  = hi + lp2;
            p  = pn;
            b0 = b0p + lpb;                          // state 0 self-loop
        };
        auto renorm = [&]() {   // p <= 3^8 between renorms, fp32-safe
            m += flog2(fmaxf(p, 1e-30f));  p = 1.0f;
        };

        for (int c = 0; c < NCH; ++c) {
            __syncthreads();                         // chunk c published
            float lp[CHUNK];
#pragma unroll
            for (int i = 0; i < CHUNK; ++i) lp[i] = buf[c & 1][i][lane];
            if (c == 0) {
                // t=0 init: alpha[1] on lane 0; b0 = blank lp (lane 1's value)
                b0 = rdlane(lp[0], 1);
                m  = (lane == 0) ? lp[0] : NEGF;
                p  = 1.0f;
#pragma unroll
                for (int i = 1; i < CHUNK; ++i) {
                    step(lp[i]);
                    if ((i & 7) == 7) renorm();
                }
            } else {
#pragma unroll
                for (int i = 0; i < CHUNK; ++i) {
                    step(lp[i]);
                    if ((i & 7) == 7) renorm();
                }
            }
        }

        // loss = -ln2 * logaddexp2(alpha2[63](=lane62), alpha2[64](=lane63))
        const float afin = m + flog2(fmaxf(p, 1e-30f));
        const float aA = rdlane(afin, 62);
        const float aB = rdlane(afin, 63);
        if (lane == 0) {
            const float h = fmaxf(aA, aB);
            const float r = h + flog2(fexp2(aA - h) + fexp2(aB - h));
            out[w] = -r * LN2F;
        }
    }
}

extern "C" void kernel_launch(void* const* d_in, const int* in_sizes, int n_in,
                              void* d_out, int out_size, void* d_ws, size_t ws_size,
                              hipStream_t stream) {
    const int*   y_true = (const int*)d_in[0];
    const float* y_pred = (const float*)d_in[1];
    float*       out    = (float*)d_out;
    ctc_fwd<<<dim3(Bb), dim3(128), 0, stream>>>(y_true, y_pred, out);
}